// Round 1
// baseline (6739.252 us; speedup 1.0000x reference)
//
#include <hip/hip_runtime.h>
#include <hip/hip_bf16.h>

#define MD 1024   // M
#define LD 1024   // L
#define ND 2048   // N

__device__ __forceinline__ float fsig(float x) { return 1.0f / (1.0f + __expf(-x)); }
__device__ __forceinline__ float ftanh_(float x) {
    float e = __expf(2.0f * x);          // overflow-safe: e=inf -> 1, e=0 -> -1
    return 1.0f - 2.0f / (e + 1.0f);
}

// XOR swizzle: spreads transposed LDS stores/reads so worst aliasing is 2-way (free).
#define SWZ(k, c) ((c) ^ (((k) & 7) << 2))

// C[i][j] (+)= sum_k A[i][k]*W[j][k] (+ bias[j]); NT layout, K%16==0, J%128==0.
// grid (J/128, ceil(I/128)), block 256. 8x8 per thread, 2x2 waves of 8x8 lanes.
__global__ __launch_bounds__(256) void gemm_nt(
    const float* __restrict__ A, int lda,
    const float* __restrict__ W, int ldw,
    const float* __restrict__ bias,
    float* __restrict__ C, int ldc,
    int I, int K, int accum)
{
    __shared__ __align__(16) float As[16][128];
    __shared__ __align__(16) float Ws[16][128];
    const int tid = threadIdx.x;
    const int j0 = blockIdx.x * 128, i0 = blockIdx.y * 128;
    const int wv = tid >> 6, lane = tid & 63;
    const int wi = wv >> 1, wj = wv & 1;
    const int li = lane >> 3, lj = lane & 7;
    const int row_r = wi * 64 + li * 8;
    const int col_r = wj * 64 + lj * 8;
    float acc[8][8] = {};
    const int lrow = tid >> 2;          // 0..63
    const int lk   = (tid & 3) << 2;    // 0,4,8,12
    const float* Ap  = A + (size_t)(i0 + lrow) * lda + lk;
    const float* Ap2 = Ap + (size_t)64 * lda;
    const float* Wp  = W + (size_t)(j0 + lrow) * ldw + lk;
    const float* Wp2 = Wp + (size_t)64 * ldw;
    const bool r0ok = (i0 + lrow) < I;
    const bool r1ok = (i0 + lrow + 64) < I;
    for (int kt = 0; kt < K; kt += 16) {
        float4 a0 = r0ok ? *(const float4*)(Ap + kt) : make_float4(0.f, 0.f, 0.f, 0.f);
        float4 a1 = r1ok ? *(const float4*)(Ap2 + kt) : make_float4(0.f, 0.f, 0.f, 0.f);
        float4 w0 = *(const float4*)(Wp + kt);
        float4 w1 = *(const float4*)(Wp2 + kt);
        __syncthreads();
        As[lk+0][SWZ(lk+0, lrow)] = a0.x;  As[lk+1][SWZ(lk+1, lrow)] = a0.y;
        As[lk+2][SWZ(lk+2, lrow)] = a0.z;  As[lk+3][SWZ(lk+3, lrow)] = a0.w;
        As[lk+0][SWZ(lk+0, lrow+64)] = a1.x;  As[lk+1][SWZ(lk+1, lrow+64)] = a1.y;
        As[lk+2][SWZ(lk+2, lrow+64)] = a1.z;  As[lk+3][SWZ(lk+3, lrow+64)] = a1.w;
        Ws[lk+0][SWZ(lk+0, lrow)] = w0.x;  Ws[lk+1][SWZ(lk+1, lrow)] = w0.y;
        Ws[lk+2][SWZ(lk+2, lrow)] = w0.z;  Ws[lk+3][SWZ(lk+3, lrow)] = w0.w;
        Ws[lk+0][SWZ(lk+0, lrow+64)] = w1.x;  Ws[lk+1][SWZ(lk+1, lrow+64)] = w1.y;
        Ws[lk+2][SWZ(lk+2, lrow+64)] = w1.z;  Ws[lk+3][SWZ(lk+3, lrow+64)] = w1.w;
        __syncthreads();
        #pragma unroll
        for (int k = 0; k < 16; k++) {
            float av[8], bv[8];
            *(float4*)&av[0] = *(const float4*)&As[k][SWZ(k, row_r)];
            *(float4*)&av[4] = *(const float4*)&As[k][SWZ(k, row_r + 4)];
            *(float4*)&bv[0] = *(const float4*)&Ws[k][SWZ(k, col_r)];
            *(float4*)&bv[4] = *(const float4*)&Ws[k][SWZ(k, col_r + 4)];
            #pragma unroll
            for (int ii = 0; ii < 8; ii++)
                #pragma unroll
                for (int jj = 0; jj < 8; jj++)
                    acc[ii][jj] = fmaf(av[ii], bv[jj], acc[ii][jj]);
        }
    }
    #pragma unroll
    for (int ii = 0; ii < 8; ii++) {
        int r = i0 + row_r + ii;
        if (r < I) {
            float* Crow = C + (size_t)r * ldc + j0 + col_r;
            #pragma unroll
            for (int jj = 0; jj < 8; jj++) {
                float v = acc[ii][jj];
                if (bias)  v += bias[j0 + col_r + jj];
                if (accum) v += Crow[jj];
                Crow[jj] = v;
            }
        }
    }
}

// Batched GEMV for small I (<=16): one j per wave, shuffle reduction. grid J/4, block 256.
template<int IMAX>
__global__ __launch_bounds__(256) void gemv_nt(
    const float* __restrict__ A, int lda, int I,
    const float* __restrict__ W, int ldw,
    const float* __restrict__ bias,
    float* __restrict__ C, int ldc, int K, int accum)
{
    const int wv = threadIdx.x >> 6, lane = threadIdx.x & 63;
    const int j = blockIdx.x * 4 + wv;
    float acc[IMAX];
    #pragma unroll
    for (int i = 0; i < IMAX; i++) acc[i] = 0.0f;
    const float* Wj = W + (size_t)j * ldw;
    for (int k = lane * 4; k < K; k += 256) {
        float4 w4 = *(const float4*)(Wj + k);
        #pragma unroll
        for (int i = 0; i < IMAX; i++) {
            if (i < I) {
                float4 a4 = *(const float4*)(A + (size_t)i * lda + k);
                acc[i] += a4.x * w4.x + a4.y * w4.y + a4.z * w4.z + a4.w * w4.w;
            }
        }
    }
    #pragma unroll
    for (int i = 0; i < IMAX; i++) {
        if (i < I) {
            float v = acc[i];
            #pragma unroll
            for (int off = 32; off >= 1; off >>= 1) v += __shfl_xor(v, off);
            if (lane == 0) {
                if (bias)  v += bias[j];
                if (accum) v += C[(size_t)i * ldc + j];
                C[(size_t)i * ldc + j] = v;
            }
        }
    }
}

// s[b][l] = sum_m Wa[m]*tanh(hw1[b][m] + HW2b[l][m]); 8 nodes/block, 8 waves.
// grid (L/64, ceil(B/8)), block 512.
__global__ __launch_bounds__(512) void attn_s(
    int B, const float* __restrict__ hw1,
    const float* __restrict__ HW2b,
    const float* __restrict__ Wa,
    float* __restrict__ S)
{
    __shared__ float s_h[8][MD];
    __shared__ float s_wa[MD];
    const int lt = blockIdx.x * 64;
    const int b0 = blockIdx.y * 8;
    const int nt = (B - b0 < 8) ? (B - b0) : 8;
    for (int idx = threadIdx.x; idx < MD; idx += 512) s_wa[idx] = Wa[idx];
    for (int i = 0; i < nt; i++)
        for (int idx = threadIdx.x; idx < MD; idx += 512)
            s_h[i][idx] = hw1[(size_t)(b0 + i) * MD + idx];
    __syncthreads();
    const int wv = threadIdx.x >> 6, lane = threadIdx.x & 63;
    for (int l = lt + wv; l < lt + 64; l += 8) {
        float acc[8] = {};
        const float* hr = HW2b + (size_t)l * MD;
        for (int mc = 0; mc < MD; mc += 64) {
            int m = mc + lane;
            float hv = hr[m];
            float wa = s_wa[m];
            #pragma unroll
            for (int i = 0; i < 8; i++)
                if (i < nt) acc[i] += wa * ftanh_(s_h[i][m] + hv);
        }
        #pragma unroll
        for (int i = 0; i < 8; i++) {
            if (i < nt) {
                float v = acc[i];
                #pragma unroll
                for (int off = 32; off >= 1; off >>= 1) v += __shfl_xor(v, off);
                if (lane == 0) S[(size_t)(b0 + i) * LD + l] = v;
            }
        }
    }
}

// In-place softmax over rows of length 1024. grid B, block 256.
__global__ __launch_bounds__(256) void softmax_rows(float* __restrict__ S)
{
    float* row = S + (size_t)blockIdx.x * LD;
    const int tid = threadIdx.x;
    const int wv = tid >> 6, lane = tid & 63;
    float v0 = row[tid], v1 = row[tid + 256], v2 = row[tid + 512], v3 = row[tid + 768];
    float mx = fmaxf(fmaxf(v0, v1), fmaxf(v2, v3));
    #pragma unroll
    for (int off = 32; off >= 1; off >>= 1) mx = fmaxf(mx, __shfl_xor(mx, off));
    __shared__ float r1[4], r2[4];
    if (lane == 0) r1[wv] = mx;
    __syncthreads();
    mx = fmaxf(fmaxf(r1[0], r1[1]), fmaxf(r1[2], r1[3]));
    float e0 = __expf(v0 - mx), e1 = __expf(v1 - mx), e2 = __expf(v2 - mx), e3 = __expf(v3 - mx);
    float sm = e0 + e1 + e2 + e3;
    #pragma unroll
    for (int off = 32; off >= 1; off >>= 1) sm += __shfl_xor(sm, off);
    if (lane == 0) r2[wv] = sm;
    __syncthreads();
    sm = r2[0] + r2[1] + r2[2] + r2[3];
    float inv = 1.0f / sm;
    row[tid] = e0 * inv; row[tid + 256] = e1 * inv;
    row[tid + 512] = e2 * inv; row[tid + 768] = e3 * inv;
}

__global__ void gather_children_k(const int* __restrict__ children, int t0,
    const float* __restrict__ Hs, float* __restrict__ hsum, float* __restrict__ hch)
{
    int b = blockIdx.y;
    int m = blockIdx.x * 256 + threadIdx.x;
    int t = t0 + b;
    int c0 = children[2 * t], c1 = children[2 * t + 1];
    float h0 = (c0 >= 0) ? Hs[(size_t)c0 * MD + m] : 0.f;
    float h1 = (c1 >= 0) ? Hs[(size_t)c1 * MD + m] : 0.f;
    hch[(size_t)(2 * b) * MD + m] = h0;
    hch[(size_t)(2 * b + 1) * MD + m] = h1;
    hsum[(size_t)b * MD + m] = h0 + h1;
}

__global__ void cell_finish_k(const int* __restrict__ children, int t0,
    const float* __restrict__ ioupre, const float* __restrict__ fpre,
    const float* __restrict__ x_f, float* __restrict__ Cmat,
    float* __restrict__ hcell)
{
    int b = blockIdx.y;
    int m = blockIdx.x * 256 + threadIdx.x;
    int t = t0 + b;
    const float* ip = ioupre + (size_t)b * 3 * MD;
    float iv = fsig(ip[m]);
    float ov = fsig(ip[MD + m]);
    float uv = ftanh_(ip[2 * MD + m]);
    float xf = x_f[(size_t)t * MD + m];
    float f0 = fsig(fpre[(size_t)(2 * b) * MD + m] + xf);
    float f1 = fsig(fpre[(size_t)(2 * b + 1) * MD + m] + xf);
    int c0 = children[2 * t], c1 = children[2 * t + 1];
    float cc0 = (c0 >= 0) ? Cmat[(size_t)c0 * MD + m] : 0.f;
    float cc1 = (c1 >= 0) ? Cmat[(size_t)c1 * MD + m] : 0.f;
    float c = iv * uv + f0 * cc0 + f1 * cc1;
    Cmat[(size_t)t * MD + m] = c;
    hcell[(size_t)b * MD + m] = ov * ftanh_(c);
}

__global__ void attn_finish_k(int t0, const float* __restrict__ hpart,
    const float* __restrict__ Hsum, const float* __restrict__ hcell,
    float* __restrict__ Hs)
{
    int b = blockIdx.y;
    int m = blockIdx.x * 256 + threadIdx.x;
    Hs[(size_t)(t0 + b) * MD + m] = Hsum[m] - hpart[(size_t)b * MD + m] + hcell[(size_t)b * MD + m];
}

__global__ void colsum_part_k(const float* __restrict__ H, float* __restrict__ part)
{
    int m = blockIdx.x * 256 + threadIdx.x;
    int lb = blockIdx.y;
    float s = 0.f;
    for (int l = lb * 64; l < lb * 64 + 64; l++) s += H[(size_t)l * MD + m];
    part[(size_t)lb * MD + m] = s;
}

__global__ void colsum_reduce_k(const float* __restrict__ part, float* __restrict__ Hsum)
{
    int m = blockIdx.x * 256 + threadIdx.x;
    float s = 0.f;
    for (int lb = 0; lb < 16; lb++) s += part[(size_t)lb * MD + m];
    Hsum[m] = s;
}

__global__ void transpose_k(const float* __restrict__ H, float* __restrict__ Ht)
{
    __shared__ float tile[32][33];
    int mb = blockIdx.x * 32, lb = blockIdx.y * 32;
    int tx = threadIdx.x, ty = threadIdx.y;
    #pragma unroll
    for (int jj = 0; jj < 4; jj++)
        tile[ty + jj * 8][tx] = H[(size_t)(lb + ty + jj * 8) * MD + mb + tx];
    __syncthreads();
    #pragma unroll
    for (int jj = 0; jj < 4; jj++)
        Ht[(size_t)(mb + ty + jj * 8) * LD + lb + tx] = tile[tx][ty + jj * 8];
}

__global__ void final_copy_k(const float* __restrict__ Cmat, float* __restrict__ out)
{
    int m = blockIdx.x * 256 + threadIdx.x;
    out[m] = Cmat[m];              // C[0]
    out[1024 + m] = out[2048 + m]; // Hs[0]
}

static inline void mm(const float* A, int lda, int I,
                      const float* W, int ldw, const float* bias,
                      float* C, int ldc, int J, int K, int accum, hipStream_t s)
{
    if (I <= 16)
        gemv_nt<16><<<J / 4, 256, 0, s>>>(A, lda, I, W, ldw, bias, C, ldc, K, accum);
    else
        gemm_nt<<<dim3(J / 128, (I + 127) / 128), 256, 0, s>>>(A, lda, W, ldw, bias, C, ldc, I, K, accum);
}

extern "C" void kernel_launch(void* const* d_in, const int* in_sizes, int n_in,
                              void* d_out, int out_size, void* d_ws, size_t ws_size,
                              hipStream_t stream)
{
    const float* inputs   = (const float*)d_in[0];
    const float* Hmat     = (const float*)d_in[1];
    const int*   children = (const int*)d_in[2];
    const float* ioux_w   = (const float*)d_in[3];
    const float* ioux_b   = (const float*)d_in[4];
    const float* iouh_w   = (const float*)d_in[5];
    const float* iouh_b   = (const float*)d_in[6];
    const float* fx_w     = (const float*)d_in[7];
    const float* fx_b     = (const float*)d_in[8];
    const float* fh_w     = (const float*)d_in[9];
    const float* fh_b     = (const float*)d_in[10];
    const float* Wa       = (const float*)d_in[11];
    const float* attnh_w  = (const float*)d_in[12];
    const float* attnh_b  = (const float*)d_in[13];

    float* out = (float*)d_out;
    float* Hs  = out + 2048;   // Hs lives directly in d_out (N*M region)

    // workspace layout (~75.6 MB of f32)
    float* p = (float*)d_ws;
    float* x_f    = p;  p += (size_t)ND * MD;
    float* HW2b   = p;  p += (size_t)LD * MD;   // H@W2^T + attnh_b
    float* Ht     = p;  p += (size_t)MD * LD;   // H transposed
    float* Hsum   = p;  p += MD;
    float* part16 = p;  p += 16 * MD;
    float* Cmat   = p;  p += (size_t)ND * MD;
    float* hsumb  = p;  p += (size_t)1024 * MD;
    float* hchb   = p;  p += (size_t)2048 * MD;
    float* ioupre = p;  p += (size_t)1024 * 3 * MD;
    float* fpre   = p;  p += (size_t)2048 * MD;
    float* hcell  = p;  p += (size_t)1024 * MD;
    float* hw1    = p;  p += (size_t)1024 * MD;
    float* Sbuf   = p;  p += (size_t)1024 * LD;
    float* hpart  = p;  p += (size_t)1024 * MD;

    // ---- precompute ----
    mm(inputs, MD, ND, fx_w, MD, fx_b, x_f, MD, MD, MD, 0, stream);                 // x_f
    mm(Hmat, MD, LD, attnh_w + MD, 2 * MD, attnh_b, HW2b, MD, MD, MD, 0, stream);   // H@W2^T + b
    colsum_part_k<<<dim3(4, 16), 256, 0, stream>>>(Hmat, part16);
    colsum_reduce_k<<<4, 256, 0, stream>>>(part16, Hsum);
    transpose_k<<<dim3(32, 32), dim3(32, 8), 0, stream>>>(Hmat, Ht);

    // ---- level-parallel tree scan (deepest first) ----
    static const int lv_t0[12] = {2047, 1023, 511, 255, 127, 63, 31, 15, 7, 3, 1, 0};
    static const int lv_B [12] = {1, 1024, 512, 256, 128, 64, 32, 16, 8, 4, 2, 1};
    for (int li = 0; li < 12; li++) {
        int t0 = lv_t0[li], B = lv_B[li];
        gather_children_k<<<dim3(4, B), 256, 0, stream>>>(children, t0, Hs, hsumb, hchb);
        // iou = hsum@iouh^T + iouh_b  (then += inputs@ioux^T + ioux_b)
        mm(hsumb, MD, B, iouh_w, MD, iouh_b, ioupre, 3 * MD, 3 * MD, MD, 0, stream);
        mm(inputs + (size_t)t0 * MD, MD, B, ioux_w, MD, ioux_b, ioupre, 3 * MD, 3 * MD, MD, 1, stream);
        // f preactivation = hch@fh^T + fh_b
        mm(hchb, MD, 2 * B, fh_w, MD, fh_b, fpre, MD, MD, MD, 0, stream);
        cell_finish_k<<<dim3(4, B), 256, 0, stream>>>(children, t0, ioupre, fpre, x_f, Cmat, hcell);
        // hw1 = hcell@W1^T
        mm(hcell, MD, B, attnh_w, 2 * MD, nullptr, hw1, MD, MD, MD, 0, stream);
        attn_s<<<dim3(LD / 64, (B + 7) / 8), 512, 0, stream>>>(B, hw1, HW2b, Wa, Sbuf);
        softmax_rows<<<B, 256, 0, stream>>>(Sbuf);
        // hpart = p@H  (via Ht, NT layout)
        mm(Sbuf, LD, B, Ht, LD, nullptr, hpart, MD, MD, LD, 0, stream);
        attn_finish_k<<<dim3(4, B), 256, 0, stream>>>(t0, hpart, Hsum, hcell, Hs);
    }
    final_copy_k<<<4, 256, 0, stream>>>(Cmat, out);
}

// Round 2
// 2928.701 us; speedup vs baseline: 2.3011x; 2.3011x over previous
//
#include <hip/hip_runtime.h>
#include <hip/hip_bf16.h>

#define MD 1024   // M
#define LD 1024   // L
#define ND 2048   // N

typedef __bf16 bf16x8 __attribute__((ext_vector_type(8)));
typedef float  f32x4  __attribute__((ext_vector_type(4)));

__device__ __forceinline__ float fsig(float x)  { return 1.0f / (1.0f + __expf(-x)); }
__device__ __forceinline__ float ftanh_(float x){ float e = __expf(2.0f * x); return 1.0f - 2.0f / (e + 1.0f); }

// ---------------- weight split: f32 -> bf16 hi + bf16 lo ----------------
__global__ void split_w_k(const float* __restrict__ src, int ld,
                          __bf16* __restrict__ dh, __bf16* __restrict__ dl, int K)
{
    int j = blockIdx.y;
    int k = blockIdx.x * 256 + threadIdx.x;
    float v = src[(size_t)j * ld + k];
    __bf16 h = (__bf16)v;
    dh[(size_t)j * K + k] = h;
    dl[(size_t)j * K + k] = (__bf16)(v - (float)h);
}

// ---------------- split-bf16 MFMA NT GEMM ----------------
// C[i][col] = scale*( sum_k A[i][k]*W[col][k] + bias[col] ) + X[i][col]
// A f32 (split in staging), W pre-split bf16 hi/lo. J = gridDim.x*128 exact.
__global__ __launch_bounds__(256) void gemm_mfma(
    const float* __restrict__ A, int lda,
    const __bf16* __restrict__ Wh, const __bf16* __restrict__ Wl,
    const float* __restrict__ bias,
    const float* __restrict__ X, int ldx,
    float* __restrict__ C, int ldc,
    int I, int K, float scale)
{
    __shared__ __align__(16) __bf16 Ash[4][128][8];
    __shared__ __align__(16) __bf16 Asl[4][128][8];
    __shared__ __align__(16) __bf16 Bsh[4][128][8];
    __shared__ __align__(16) __bf16 Bsl[4][128][8];
    const int tid = threadIdx.x;
    const int j0 = blockIdx.x * 128, i0 = blockIdx.y * 128;
    const int lane = tid & 63, wv = tid >> 6;
    const int wm = wv >> 1, wn = wv & 1;
    const int g = lane >> 4, fr = lane & 15;

    f32x4 acc[4][4];
    #pragma unroll
    for (int m = 0; m < 4; m++)
        #pragma unroll
        for (int n = 0; n < 4; n++)
            acc[m][n] = (f32x4){0.f, 0.f, 0.f, 0.f};

    const int srow = tid >> 1;
    const int kh   = (tid & 1) * 16;
    const int g0   = kh >> 3;
    const float*  Arow  = A  + (size_t)(i0 + srow) * lda + kh;
    const __bf16* Whrow = Wh + (size_t)(j0 + srow) * K + kh;
    const __bf16* Wlrow = Wl + (size_t)(j0 + srow) * K + kh;
    const bool rowok = (i0 + srow) < I;

    for (int kt = 0; kt < K; kt += 32) {
        float v[16];
        if (rowok) {
            *(float4*)&v[0]  = *(const float4*)(Arow + kt);
            *(float4*)&v[4]  = *(const float4*)(Arow + kt + 4);
            *(float4*)&v[8]  = *(const float4*)(Arow + kt + 8);
            *(float4*)&v[12] = *(const float4*)(Arow + kt + 12);
        } else {
            #pragma unroll
            for (int q = 0; q < 16; q++) v[q] = 0.f;
        }
        bf16x8 h0, h1, l0, l1;
        #pragma unroll
        for (int q = 0; q < 8; q++) {
            float f = v[q];       __bf16 hb = (__bf16)f;
            h0[q] = hb; l0[q] = (__bf16)(f - (float)hb);
        }
        #pragma unroll
        for (int q = 0; q < 8; q++) {
            float f = v[8 + q];   __bf16 hb = (__bf16)f;
            h1[q] = hb; l1[q] = (__bf16)(f - (float)hb);
        }
        bf16x8 wh0 = *(const bf16x8*)(Whrow + kt);
        bf16x8 wh1 = *(const bf16x8*)(Whrow + kt + 8);
        bf16x8 wl0 = *(const bf16x8*)(Wlrow + kt);
        bf16x8 wl1 = *(const bf16x8*)(Wlrow + kt + 8);
        __syncthreads();
        *(bf16x8*)&Ash[g0][srow][0]     = h0;
        *(bf16x8*)&Ash[g0 + 1][srow][0] = h1;
        *(bf16x8*)&Asl[g0][srow][0]     = l0;
        *(bf16x8*)&Asl[g0 + 1][srow][0] = l1;
        *(bf16x8*)&Bsh[g0][srow][0]     = wh0;
        *(bf16x8*)&Bsh[g0 + 1][srow][0] = wh1;
        *(bf16x8*)&Bsl[g0][srow][0]     = wl0;
        *(bf16x8*)&Bsl[g0 + 1][srow][0] = wl1;
        __syncthreads();

        bf16x8 ah[4], al[4], bh[4], bl[4];
        #pragma unroll
        for (int m = 0; m < 4; m++) {
            ah[m] = *(bf16x8*)&Ash[g][wm * 64 + m * 16 + fr][0];
            al[m] = *(bf16x8*)&Asl[g][wm * 64 + m * 16 + fr][0];
        }
        #pragma unroll
        for (int n = 0; n < 4; n++) {
            bh[n] = *(bf16x8*)&Bsh[g][wn * 64 + n * 16 + fr][0];
            bl[n] = *(bf16x8*)&Bsl[g][wn * 64 + n * 16 + fr][0];
        }
        #pragma unroll
        for (int m = 0; m < 4; m++)
            #pragma unroll
            for (int n = 0; n < 4; n++) {
                acc[m][n] = __builtin_amdgcn_mfma_f32_16x16x32_bf16(ah[m], bh[n], acc[m][n], 0, 0, 0);
                acc[m][n] = __builtin_amdgcn_mfma_f32_16x16x32_bf16(ah[m], bl[n], acc[m][n], 0, 0, 0);
                acc[m][n] = __builtin_amdgcn_mfma_f32_16x16x32_bf16(al[m], bh[n], acc[m][n], 0, 0, 0);
            }
    }

    #pragma unroll
    for (int m = 0; m < 4; m++) {
        int rbase = i0 + wm * 64 + m * 16 + g * 4;
        #pragma unroll
        for (int n = 0; n < 4; n++) {
            int col = j0 + wn * 64 + n * 16 + fr;
            float b = bias ? bias[col] : 0.f;
            #pragma unroll
            for (int j = 0; j < 4; j++) {
                int r = rbase + j;
                if (r < I) {
                    float val = (acc[m][n][j] + b) * scale;
                    if (X) val += X[(size_t)r * ldx + col];
                    C[(size_t)r * ldc + col] = val;
                }
            }
        }
    }
}

// ---------------- f32 batched GEMV for tiny I ----------------
template<int IMAX>
__global__ __launch_bounds__(256) void gemv_nt(
    const float* __restrict__ A, int lda, int I,
    const float* __restrict__ W, int ldw,
    const float* __restrict__ bias,
    const float* __restrict__ X, int ldx,
    float* __restrict__ C, int ldc, int K, float scale)
{
    const int wv = threadIdx.x >> 6, lane = threadIdx.x & 63;
    const int j = blockIdx.x * 4 + wv;
    float acc[IMAX];
    #pragma unroll
    for (int i = 0; i < IMAX; i++) acc[i] = 0.0f;
    const float* Wj = W + (size_t)j * ldw;
    for (int k = lane * 4; k < K; k += 256) {
        float4 w4 = *(const float4*)(Wj + k);
        #pragma unroll
        for (int i = 0; i < IMAX; i++) {
            if (i < I) {
                float4 a4 = *(const float4*)(A + (size_t)i * lda + k);
                acc[i] += a4.x * w4.x + a4.y * w4.y + a4.z * w4.z + a4.w * w4.w;
            }
        }
    }
    #pragma unroll
    for (int i = 0; i < IMAX; i++) {
        if (i < I) {
            float v = acc[i];
            #pragma unroll
            for (int off = 32; off >= 1; off >>= 1) v += __shfl_xor(v, off);
            if (lane == 0) {
                float v2 = (v + (bias ? bias[j] : 0.f)) * scale;
                if (X) v2 += X[(size_t)i * ldx + j];
                C[(size_t)i * ldc + j] = v2;
            }
        }
    }
}

// ---------------- attention scores ----------------
// hw1/HW2c are pre-scaled by 2; s[l] = S_wa - 2*sum_m wa[m]/(1+exp(2x))
__global__ __launch_bounds__(512) void attn_s(
    int B, const float* __restrict__ hw1,
    const float* __restrict__ HW2c,
    const float* __restrict__ s_wa_sum,
    const float* __restrict__ Wa,
    float* __restrict__ S)
{
    __shared__ float s_h[8][MD];
    __shared__ float s_wa[MD];
    const int lt = blockIdx.x * 64;
    const int b0 = blockIdx.y * 8;
    const int nt = (B - b0 < 8) ? (B - b0) : 8;
    for (int idx = threadIdx.x; idx < MD; idx += 512) s_wa[idx] = Wa[idx];
    for (int i = 0; i < nt; i++)
        for (int idx = threadIdx.x; idx < MD; idx += 512)
            s_h[i][idx] = hw1[(size_t)(b0 + i) * MD + idx];
    __syncthreads();
    const int wv = threadIdx.x >> 6, lane = threadIdx.x & 63;
    const float swa = s_wa_sum[0];
    for (int l = lt + wv; l < lt + 64; l += 8) {
        float acc[8] = {};
        const float* hr = HW2c + (size_t)l * MD;
        for (int mc = 0; mc < MD; mc += 256) {
            const int m = mc + lane * 4;
            float4 hv  = *(const float4*)(hr + m);
            float4 wa4 = *(const float4*)&s_wa[m];
            #pragma unroll
            for (int i = 0; i < 8; i++) {
                if (i < nt) {
                    float4 sh = *(const float4*)&s_h[i][m];
                    float e, r;
                    e = __expf(sh.x + hv.x); r = __builtin_amdgcn_rcpf(1.0f + e); acc[i] = fmaf(wa4.x, r, acc[i]);
                    e = __expf(sh.y + hv.y); r = __builtin_amdgcn_rcpf(1.0f + e); acc[i] = fmaf(wa4.y, r, acc[i]);
                    e = __expf(sh.z + hv.z); r = __builtin_amdgcn_rcpf(1.0f + e); acc[i] = fmaf(wa4.z, r, acc[i]);
                    e = __expf(sh.w + hv.w); r = __builtin_amdgcn_rcpf(1.0f + e); acc[i] = fmaf(wa4.w, r, acc[i]);
                }
            }
        }
        #pragma unroll
        for (int i = 0; i < 8; i++) {
            if (i < nt) {
                float v = acc[i];
                #pragma unroll
                for (int off = 32; off >= 1; off >>= 1) v += __shfl_xor(v, off);
                if (lane == 0) S[(size_t)(b0 + i) * LD + l] = swa - 2.0f * v;
            }
        }
    }
}

__global__ __launch_bounds__(256) void softmax_rows(float* __restrict__ S)
{
    float* row = S + (size_t)blockIdx.x * LD;
    const int tid = threadIdx.x;
    const int wv = tid >> 6, lane = tid & 63;
    float v0 = row[tid], v1 = row[tid + 256], v2 = row[tid + 512], v3 = row[tid + 768];
    float mx = fmaxf(fmaxf(v0, v1), fmaxf(v2, v3));
    #pragma unroll
    for (int off = 32; off >= 1; off >>= 1) mx = fmaxf(mx, __shfl_xor(mx, off));
    __shared__ float r1[4], r2[4];
    if (lane == 0) r1[wv] = mx;
    __syncthreads();
    mx = fmaxf(fmaxf(r1[0], r1[1]), fmaxf(r1[2], r1[3]));
    float e0 = __expf(v0 - mx), e1 = __expf(v1 - mx), e2 = __expf(v2 - mx), e3 = __expf(v3 - mx);
    float sm = e0 + e1 + e2 + e3;
    #pragma unroll
    for (int off = 32; off >= 1; off >>= 1) sm += __shfl_xor(sm, off);
    if (lane == 0) r2[wv] = sm;
    __syncthreads();
    sm = r2[0] + r2[1] + r2[2] + r2[3];
    float inv = 1.0f / sm;
    row[tid] = e0 * inv; row[tid + 256] = e1 * inv;
    row[tid + 512] = e2 * inv; row[tid + 768] = e3 * inv;
}

// ---------------- elementwise / tree plumbing ----------------
__global__ void gather_children_k(const int* __restrict__ children, int t0,
    const float* __restrict__ Hs, float* __restrict__ hsum, float* __restrict__ hch)
{
    int b = blockIdx.y;
    int m = blockIdx.x * 256 + threadIdx.x;
    int t = t0 + b;
    int c0 = children[2 * t], c1 = children[2 * t + 1];
    float h0 = (c0 >= 0) ? Hs[(size_t)c0 * MD + m] : 0.f;
    float h1 = (c1 >= 0) ? Hs[(size_t)c1 * MD + m] : 0.f;
    hch[(size_t)(2 * b) * MD + m] = h0;
    hch[(size_t)(2 * b + 1) * MD + m] = h1;
    hsum[(size_t)b * MD + m] = h0 + h1;
}

__global__ void cell_finish_k(const int* __restrict__ children, int t0,
    const float* __restrict__ ioupre, const float* __restrict__ fpre,
    const float* __restrict__ x_f, float* __restrict__ Cmat,
    float* __restrict__ hcell)
{
    int b = blockIdx.y;
    int m = blockIdx.x * 256 + threadIdx.x;
    int t = t0 + b;
    const float* ip = ioupre + (size_t)b * 3 * MD;
    float iv = fsig(ip[m]);
    float ov = fsig(ip[MD + m]);
    float uv = ftanh_(ip[2 * MD + m]);
    float xf = x_f[(size_t)t * MD + m];
    float f0 = fsig(fpre[(size_t)(2 * b) * MD + m] + xf);
    float f1 = fsig(fpre[(size_t)(2 * b + 1) * MD + m] + xf);
    int c0 = children[2 * t], c1 = children[2 * t + 1];
    float cc0 = (c0 >= 0) ? Cmat[(size_t)c0 * MD + m] : 0.f;
    float cc1 = (c1 >= 0) ? Cmat[(size_t)c1 * MD + m] : 0.f;
    float c = iv * uv + f0 * cc0 + f1 * cc1;
    Cmat[(size_t)t * MD + m] = c;
    hcell[(size_t)b * MD + m] = ov * ftanh_(c);
}

__global__ void attn_finish_k(int t0, const float* __restrict__ hpart,
    const float* __restrict__ Hsum, const float* __restrict__ hcell,
    float* __restrict__ Hs)
{
    int b = blockIdx.y;
    int m = blockIdx.x * 256 + threadIdx.x;
    Hs[(size_t)(t0 + b) * MD + m] = Hsum[m] - hpart[(size_t)b * MD + m] + hcell[(size_t)b * MD + m];
}

__global__ void colsum_part_k(const float* __restrict__ H, float* __restrict__ part)
{
    int m = blockIdx.x * 256 + threadIdx.x;
    int lb = blockIdx.y;
    float s = 0.f;
    for (int l = lb * 64; l < lb * 64 + 64; l++) s += H[(size_t)l * MD + m];
    part[(size_t)lb * MD + m] = s;
}

__global__ void colsum_reduce_k(const float* __restrict__ part, float* __restrict__ Hsum)
{
    int m = blockIdx.x * 256 + threadIdx.x;
    float s = 0.f;
    for (int lb = 0; lb < 16; lb++) s += part[(size_t)lb * MD + m];
    Hsum[m] = s;
}

__global__ void transpose_split_k(const float* __restrict__ H, float* __restrict__ Ht,
                                  __bf16* __restrict__ Hth, __bf16* __restrict__ Htl)
{
    __shared__ float tile[32][33];
    int mb = blockIdx.x * 32, lb = blockIdx.y * 32;
    int tx = threadIdx.x, ty = threadIdx.y;
    #pragma unroll
    for (int jj = 0; jj < 4; jj++)
        tile[ty + jj * 8][tx] = H[(size_t)(lb + ty + jj * 8) * MD + mb + tx];
    __syncthreads();
    #pragma unroll
    for (int jj = 0; jj < 4; jj++) {
        float v = tile[tx][ty + jj * 8];
        size_t idx = (size_t)(mb + ty + jj * 8) * LD + lb + tx;
        Ht[idx] = v;
        __bf16 h = (__bf16)v;
        Hth[idx] = h;
        Htl[idx] = (__bf16)(v - (float)h);
    }
}

__global__ void sumwa_k(const float* __restrict__ Wa, float* __restrict__ out)
{
    int tid = threadIdx.x;
    float v = Wa[tid] + Wa[tid + 256] + Wa[tid + 512] + Wa[tid + 768];
    #pragma unroll
    for (int off = 32; off >= 1; off >>= 1) v += __shfl_xor(v, off);
    __shared__ float r[4];
    if ((tid & 63) == 0) r[tid >> 6] = v;
    __syncthreads();
    if (tid == 0) out[0] = r[0] + r[1] + r[2] + r[3];
}

__global__ void final_copy_k(const float* __restrict__ Cmat, float* __restrict__ out)
{
    int m = blockIdx.x * 256 + threadIdx.x;
    out[m] = Cmat[m];              // C[0]
    out[1024 + m] = out[2048 + m]; // Hs[0]
}

// ---------------- dispatch helper ----------------
static inline void mmx(const float* A, int lda, int I,
                       const float* Wf, int ldwf,
                       const __bf16* Wh, const __bf16* Wl,
                       const float* bias, const float* X, int ldx,
                       float* C, int ldc, int J, int K, float scale, hipStream_t s)
{
    if (I <= 32)
        gemv_nt<32><<<J / 4, 256, 0, s>>>(A, lda, I, Wf, ldwf, bias, X, ldx, C, ldc, K, scale);
    else
        gemm_mfma<<<dim3(J / 128, (I + 127) / 128), 256, 0, s>>>(A, lda, Wh, Wl, bias, X, ldx, C, ldc, I, K, scale);
}

extern "C" void kernel_launch(void* const* d_in, const int* in_sizes, int n_in,
                              void* d_out, int out_size, void* d_ws, size_t ws_size,
                              hipStream_t stream)
{
    const float* inputs   = (const float*)d_in[0];
    const float* Hmat     = (const float*)d_in[1];
    const int*   children = (const int*)d_in[2];
    const float* ioux_w   = (const float*)d_in[3];
    const float* ioux_b   = (const float*)d_in[4];
    const float* iouh_w   = (const float*)d_in[5];
    const float* iouh_b   = (const float*)d_in[6];
    const float* fx_w     = (const float*)d_in[7];
    const float* fx_b     = (const float*)d_in[8];
    const float* fh_w     = (const float*)d_in[9];
    const float* fh_b     = (const float*)d_in[10];
    const float* Wa       = (const float*)d_in[11];
    const float* attnh_w  = (const float*)d_in[12];
    const float* attnh_b  = (const float*)d_in[13];

    float* out = (float*)d_out;
    float* Hs  = out + 2048;   // Hs (N*M) lives in d_out

    // ---- workspace layout ----
    float* p = (float*)d_ws;
    float* x_f    = p;  p += (size_t)ND * MD;          // 2M
    float* x_iou  = p;  p += (size_t)ND * 3 * MD;      // 6M
    float* HW2c   = p;  p += (size_t)LD * MD;          // 1M  (2*(H@W2^T + b))
    float* Ht     = p;  p += (size_t)MD * LD;          // 1M
    float* Cmat   = p;  p += (size_t)ND * MD;          // 2M
    float* hsumb  = p;  p += (size_t)1024 * MD;        // 1M
    float* hchb   = p;  p += (size_t)2048 * MD;        // 2M
    float* ioupre = p;  p += (size_t)1024 * 3 * MD;    // 3M
    float* fpre   = p;  p += (size_t)2048 * MD;        // 2M
    float* hcell  = p;  p += (size_t)1024 * MD;        // 1M
    float* hw1b   = p;  p += (size_t)1024 * MD;        // 1M
    float* Sbuf   = p;  p += (size_t)1024 * LD;        // 1M
    float* hpart  = p;  p += (size_t)1024 * MD;        // 1M
    float* Hsum   = p;  p += MD;
    float* part16 = p;  p += 16 * MD;
    float* S_wa   = p;  p += 8;
    __bf16* q = (__bf16*)p;
    __bf16* iouhH = q; q += (size_t)3 * MD * MD;
    __bf16* iouhL = q; q += (size_t)3 * MD * MD;
    __bf16* iouxH = q; q += (size_t)3 * MD * MD;
    __bf16* iouxL = q; q += (size_t)3 * MD * MD;
    __bf16* fxH   = q; q += (size_t)MD * MD;
    __bf16* fxL   = q; q += (size_t)MD * MD;
    __bf16* fhH   = q; q += (size_t)MD * MD;
    __bf16* fhL   = q; q += (size_t)MD * MD;
    __bf16* W1H   = q; q += (size_t)MD * MD;
    __bf16* W1L   = q; q += (size_t)MD * MD;
    __bf16* W2H   = q; q += (size_t)MD * MD;
    __bf16* W2L   = q; q += (size_t)MD * MD;
    __bf16* HtH   = q; q += (size_t)MD * LD;
    __bf16* HtL   = q; q += (size_t)MD * LD;

    // ---- one-time: splits & precomputes ----
    split_w_k<<<dim3(4, 3 * MD), 256, 0, stream>>>(iouh_w, MD, iouhH, iouhL, MD);
    split_w_k<<<dim3(4, 3 * MD), 256, 0, stream>>>(ioux_w, MD, iouxH, iouxL, MD);
    split_w_k<<<dim3(4, MD), 256, 0, stream>>>(fx_w, MD, fxH, fxL, MD);
    split_w_k<<<dim3(4, MD), 256, 0, stream>>>(fh_w, MD, fhH, fhL, MD);
    split_w_k<<<dim3(4, MD), 256, 0, stream>>>(attnh_w, 2 * MD, W1H, W1L, MD);
    split_w_k<<<dim3(4, MD), 256, 0, stream>>>(attnh_w + MD, 2 * MD, W2H, W2L, MD);
    transpose_split_k<<<dim3(32, 32), dim3(32, 8), 0, stream>>>(Hmat, Ht, HtH, HtL);
    sumwa_k<<<1, 256, 0, stream>>>(Wa, S_wa);
    colsum_part_k<<<dim3(4, 16), 256, 0, stream>>>(Hmat, part16);
    colsum_reduce_k<<<4, 256, 0, stream>>>(part16, Hsum);

    // x_f = inputs@fx^T + fx_b ; x_iou = inputs@ioux^T + ioux_b
    gemm_mfma<<<dim3(8, 16), 256, 0, stream>>>(inputs, MD, fxH, fxL, fx_b, nullptr, 0, x_f, MD, ND, MD, 1.0f);
    gemm_mfma<<<dim3(24, 16), 256, 0, stream>>>(inputs, MD, iouxH, iouxL, ioux_b, nullptr, 0, x_iou, 3 * MD, ND, MD, 1.0f);
    // HW2c = 2*(H@W2^T + attnh_b)   (pre-scaled for the exp-based tanh)
    gemm_mfma<<<dim3(8, 8), 256, 0, stream>>>(Hmat, MD, W2H, W2L, attnh_b, nullptr, 0, HW2c, MD, LD, MD, 2.0f);

    // ---- level-parallel tree scan (deepest first) ----
    static const int lv_t0[12] = {2047, 1023, 511, 255, 127, 63, 31, 15, 7, 3, 1, 0};
    static const int lv_B [12] = {1, 1024, 512, 256, 128, 64, 32, 16, 8, 4, 2, 1};
    for (int li = 0; li < 12; li++) {
        int t0 = lv_t0[li], B = lv_B[li];
        gather_children_k<<<dim3(4, B), 256, 0, stream>>>(children, t0, Hs, hsumb, hchb);
        // iou = hsum@iouh^T + iouh_b + x_iou[t0..]
        mmx(hsumb, MD, B, iouh_w, MD, iouhH, iouhL, iouh_b,
            x_iou + (size_t)t0 * 3 * MD, 3 * MD, ioupre, 3 * MD, 3 * MD, MD, 1.0f, stream);
        // fpre = hch@fh^T + fh_b
        mmx(hchb, MD, 2 * B, fh_w, MD, fhH, fhL, fh_b, nullptr, 0, fpre, MD, MD, MD, 1.0f, stream);
        cell_finish_k<<<dim3(4, B), 256, 0, stream>>>(children, t0, ioupre, fpre, x_f, Cmat, hcell);
        // hw1 = 2*(hcell@W1^T)
        mmx(hcell, MD, B, attnh_w, 2 * MD, W1H, W1L, nullptr, nullptr, 0, hw1b, MD, MD, MD, 2.0f, stream);
        attn_s<<<dim3(LD / 64, (B + 7) / 8), 512, 0, stream>>>(B, hw1b, HW2c, S_wa, Wa, Sbuf);
        softmax_rows<<<B, 256, 0, stream>>>(Sbuf);
        // hpart = p@H (via Ht)
        mmx(Sbuf, LD, B, Ht, LD, HtH, HtL, nullptr, nullptr, 0, hpart, MD, MD, LD, 1.0f, stream);
        attn_finish_k<<<dim3(4, B), 256, 0, stream>>>(t0, hpart, Hsum, hcell, Hs);
    }
    final_copy_k<<<4, 256, 0, stream>>>(Cmat, out);
}

// Round 3
// 1905.902 us; speedup vs baseline: 3.5360x; 1.5366x over previous
//
#include <hip/hip_runtime.h>
#include <hip/hip_bf16.h>

#define MD 1024   // M
#define LD 1024   // L
#define ND 2048   // N

typedef __bf16 bf16x8 __attribute__((ext_vector_type(8)));
typedef float  f32x4  __attribute__((ext_vector_type(4)));

__device__ __forceinline__ float fsig(float x)  { return 1.0f / (1.0f + __expf(-x)); }
__device__ __forceinline__ float ftanh_(float x){ float e = __expf(2.0f * x); return 1.0f - 2.0f / (e + 1.0f); }

// epilogue: val = (acc + bias)*scale (+X); if expm -> exp(clamp(val,±80))
__device__ __forceinline__ float epival(float acc, float b, float scale,
                                        const float* X, size_t xi, int expm)
{
    float v = (acc + b) * scale;
    if (X) v += X[xi];
    if (expm) v = __expf(fminf(fmaxf(v, -80.f), 80.f));
    return v;
}

// ---------------- weight split: f32 -> bf16 hi + bf16 lo ----------------
__global__ void split_w_k(const float* __restrict__ src, int ld,
                          __bf16* __restrict__ dh, __bf16* __restrict__ dl, int K)
{
    int j = blockIdx.y;
    int k = blockIdx.x * 256 + threadIdx.x;
    float v = src[(size_t)j * ld + k];
    __bf16 h = (__bf16)v;
    dh[(size_t)j * K + k] = h;
    dl[(size_t)j * K + k] = (__bf16)(v - (float)h);
}

// ---------------- split-bf16 MFMA NT GEMM, 128x128 tile ----------------
__global__ __launch_bounds__(256) void gemm_mfma(
    const float* __restrict__ A, int lda,
    const __bf16* __restrict__ Wh, const __bf16* __restrict__ Wl,
    const float* __restrict__ bias,
    const float* __restrict__ X, int ldx,
    float* __restrict__ C, int ldc,
    int I, int K, float scale, int expm)
{
    __shared__ __align__(16) __bf16 Ash[4][128][8];
    __shared__ __align__(16) __bf16 Asl[4][128][8];
    __shared__ __align__(16) __bf16 Bsh[4][128][8];
    __shared__ __align__(16) __bf16 Bsl[4][128][8];
    const int tid = threadIdx.x;
    const int j0 = blockIdx.x * 128, i0 = blockIdx.y * 128;
    const int lane = tid & 63, wv = tid >> 6;
    const int wm = wv >> 1, wn = wv & 1;
    const int g = lane >> 4, fr = lane & 15;

    f32x4 acc[4][4];
    #pragma unroll
    for (int m = 0; m < 4; m++)
        #pragma unroll
        for (int n = 0; n < 4; n++)
            acc[m][n] = (f32x4){0.f, 0.f, 0.f, 0.f};

    const int srow = tid >> 1;
    const int kh   = (tid & 1) * 16;
    const int g0   = kh >> 3;
    const float*  Arow  = A  + (size_t)(i0 + srow) * lda + kh;
    const __bf16* Whrow = Wh + (size_t)(j0 + srow) * K + kh;
    const __bf16* Wlrow = Wl + (size_t)(j0 + srow) * K + kh;
    const bool rowok = (i0 + srow) < I;

    for (int kt = 0; kt < K; kt += 32) {
        float v[16];
        if (rowok) {
            *(float4*)&v[0]  = *(const float4*)(Arow + kt);
            *(float4*)&v[4]  = *(const float4*)(Arow + kt + 4);
            *(float4*)&v[8]  = *(const float4*)(Arow + kt + 8);
            *(float4*)&v[12] = *(const float4*)(Arow + kt + 12);
        } else {
            #pragma unroll
            for (int q = 0; q < 16; q++) v[q] = 0.f;
        }
        bf16x8 h0, h1, l0, l1;
        #pragma unroll
        for (int q = 0; q < 8; q++) {
            float f = v[q];       __bf16 hb = (__bf16)f;
            h0[q] = hb; l0[q] = (__bf16)(f - (float)hb);
        }
        #pragma unroll
        for (int q = 0; q < 8; q++) {
            float f = v[8 + q];   __bf16 hb = (__bf16)f;
            h1[q] = hb; l1[q] = (__bf16)(f - (float)hb);
        }
        bf16x8 wh0 = *(const bf16x8*)(Whrow + kt);
        bf16x8 wh1 = *(const bf16x8*)(Whrow + kt + 8);
        bf16x8 wl0 = *(const bf16x8*)(Wlrow + kt);
        bf16x8 wl1 = *(const bf16x8*)(Wlrow + kt + 8);
        __syncthreads();
        *(bf16x8*)&Ash[g0][srow][0]     = h0;
        *(bf16x8*)&Ash[g0 + 1][srow][0] = h1;
        *(bf16x8*)&Asl[g0][srow][0]     = l0;
        *(bf16x8*)&Asl[g0 + 1][srow][0] = l1;
        *(bf16x8*)&Bsh[g0][srow][0]     = wh0;
        *(bf16x8*)&Bsh[g0 + 1][srow][0] = wh1;
        *(bf16x8*)&Bsl[g0][srow][0]     = wl0;
        *(bf16x8*)&Bsl[g0 + 1][srow][0] = wl1;
        __syncthreads();

        bf16x8 ah[4], al[4], bh[4], bl[4];
        #pragma unroll
        for (int m = 0; m < 4; m++) {
            ah[m] = *(bf16x8*)&Ash[g][wm * 64 + m * 16 + fr][0];
            al[m] = *(bf16x8*)&Asl[g][wm * 64 + m * 16 + fr][0];
        }
        #pragma unroll
        for (int n = 0; n < 4; n++) {
            bh[n] = *(bf16x8*)&Bsh[g][wn * 64 + n * 16 + fr][0];
            bl[n] = *(bf16x8*)&Bsl[g][wn * 64 + n * 16 + fr][0];
        }
        #pragma unroll
        for (int m = 0; m < 4; m++)
            #pragma unroll
            for (int n = 0; n < 4; n++) {
                acc[m][n] = __builtin_amdgcn_mfma_f32_16x16x32_bf16(ah[m], bh[n], acc[m][n], 0, 0, 0);
                acc[m][n] = __builtin_amdgcn_mfma_f32_16x16x32_bf16(ah[m], bl[n], acc[m][n], 0, 0, 0);
                acc[m][n] = __builtin_amdgcn_mfma_f32_16x16x32_bf16(al[m], bh[n], acc[m][n], 0, 0, 0);
            }
    }

    #pragma unroll
    for (int m = 0; m < 4; m++) {
        int rbase = i0 + wm * 64 + m * 16 + g * 4;
        #pragma unroll
        for (int n = 0; n < 4; n++) {
            int col = j0 + wn * 64 + n * 16 + fr;
            float b = bias ? bias[col] : 0.f;
            #pragma unroll
            for (int j = 0; j < 4; j++) {
                int r = rbase + j;
                if (r < I)
                    C[(size_t)r * ldc + col] =
                        epival(acc[m][n][j], b, scale, X, (size_t)r * ldx + col, expm);
            }
        }
    }
}

// ---------------- split-bf16 MFMA NT GEMM, 64x64 tile (skinny shapes) ----------------
__global__ __launch_bounds__(256) void gemm64_mfma(
    const float* __restrict__ A, int lda,
    const __bf16* __restrict__ Wh, const __bf16* __restrict__ Wl,
    const float* __restrict__ bias,
    const float* __restrict__ X, int ldx,
    float* __restrict__ C, int ldc,
    int I, int K, float scale, int expm)
{
    __shared__ __align__(16) __bf16 Ash[4][64][8];
    __shared__ __align__(16) __bf16 Asl[4][64][8];
    __shared__ __align__(16) __bf16 Bsh[4][64][8];
    __shared__ __align__(16) __bf16 Bsl[4][64][8];
    const int tid = threadIdx.x;
    const int j0 = blockIdx.x * 64, i0 = blockIdx.y * 64;
    const int lane = tid & 63, wv = tid >> 6;
    const int wm = wv >> 1, wn = wv & 1;
    const int g = lane >> 4, fr = lane & 15;

    f32x4 acc[2][2];
    #pragma unroll
    for (int m = 0; m < 2; m++)
        #pragma unroll
        for (int n = 0; n < 2; n++)
            acc[m][n] = (f32x4){0.f, 0.f, 0.f, 0.f};

    const int srow = tid >> 2;        // 0..63
    const int kh   = (tid & 3) * 8;   // 0,8,16,24
    const int g0   = kh >> 3;         // 0..3
    const float*  Arow  = A  + (size_t)(i0 + srow) * lda + kh;
    const __bf16* Whrow = Wh + (size_t)(j0 + srow) * K + kh;
    const __bf16* Wlrow = Wl + (size_t)(j0 + srow) * K + kh;
    const bool rowok = (i0 + srow) < I;

    for (int kt = 0; kt < K; kt += 32) {
        float v[8];
        if (rowok) {
            *(float4*)&v[0] = *(const float4*)(Arow + kt);
            *(float4*)&v[4] = *(const float4*)(Arow + kt + 4);
        } else {
            #pragma unroll
            for (int q = 0; q < 8; q++) v[q] = 0.f;
        }
        bf16x8 h0, l0;
        #pragma unroll
        for (int q = 0; q < 8; q++) {
            float f = v[q]; __bf16 hb = (__bf16)f;
            h0[q] = hb; l0[q] = (__bf16)(f - (float)hb);
        }
        bf16x8 wh0 = *(const bf16x8*)(Whrow + kt);
        bf16x8 wl0 = *(const bf16x8*)(Wlrow + kt);
        __syncthreads();
        *(bf16x8*)&Ash[g0][srow][0] = h0;
        *(bf16x8*)&Asl[g0][srow][0] = l0;
        *(bf16x8*)&Bsh[g0][srow][0] = wh0;
        *(bf16x8*)&Bsl[g0][srow][0] = wl0;
        __syncthreads();

        bf16x8 ah[2], al[2], bh[2], bl[2];
        #pragma unroll
        for (int m = 0; m < 2; m++) {
            ah[m] = *(bf16x8*)&Ash[g][wm * 32 + m * 16 + fr][0];
            al[m] = *(bf16x8*)&Asl[g][wm * 32 + m * 16 + fr][0];
        }
        #pragma unroll
        for (int n = 0; n < 2; n++) {
            bh[n] = *(bf16x8*)&Bsh[g][wn * 32 + n * 16 + fr][0];
            bl[n] = *(bf16x8*)&Bsl[g][wn * 32 + n * 16 + fr][0];
        }
        #pragma unroll
        for (int m = 0; m < 2; m++)
            #pragma unroll
            for (int n = 0; n < 2; n++) {
                acc[m][n] = __builtin_amdgcn_mfma_f32_16x16x32_bf16(ah[m], bh[n], acc[m][n], 0, 0, 0);
                acc[m][n] = __builtin_amdgcn_mfma_f32_16x16x32_bf16(ah[m], bl[n], acc[m][n], 0, 0, 0);
                acc[m][n] = __builtin_amdgcn_mfma_f32_16x16x32_bf16(al[m], bh[n], acc[m][n], 0, 0, 0);
            }
    }

    #pragma unroll
    for (int m = 0; m < 2; m++) {
        int rbase = i0 + wm * 32 + m * 16 + g * 4;
        #pragma unroll
        for (int n = 0; n < 2; n++) {
            int col = j0 + wn * 32 + n * 16 + fr;
            float b = bias ? bias[col] : 0.f;
            #pragma unroll
            for (int j = 0; j < 4; j++) {
                int r = rbase + j;
                if (r < I)
                    C[(size_t)r * ldc + col] =
                        epival(acc[m][n][j], b, scale, X, (size_t)r * ldx + col, expm);
            }
        }
    }
}

// ---------------- f32 batched GEMV for tiny I ----------------
template<int IMAX>
__global__ __launch_bounds__(256) void gemv_nt(
    const float* __restrict__ A, int lda, int I,
    const float* __restrict__ W, int ldw,
    const float* __restrict__ bias,
    const float* __restrict__ X, int ldx,
    float* __restrict__ C, int ldc, int K, float scale, int expm)
{
    const int wv = threadIdx.x >> 6, lane = threadIdx.x & 63;
    const int j = blockIdx.x * 4 + wv;
    float acc[IMAX];
    #pragma unroll
    for (int i = 0; i < IMAX; i++) acc[i] = 0.0f;
    const float* Wj = W + (size_t)j * ldw;
    for (int k = lane * 4; k < K; k += 256) {
        float4 w4 = *(const float4*)(Wj + k);
        #pragma unroll
        for (int i = 0; i < IMAX; i++) {
            if (i < I) {
                float4 a4 = *(const float4*)(A + (size_t)i * lda + k);
                acc[i] += a4.x * w4.x + a4.y * w4.y + a4.z * w4.z + a4.w * w4.w;
            }
        }
    }
    #pragma unroll
    for (int i = 0; i < IMAX; i++) {
        if (i < I) {
            float v = acc[i];
            #pragma unroll
            for (int off = 32; off >= 1; off >>= 1) v += __shfl_xor(v, off);
            if (lane == 0)
                C[(size_t)i * ldc + j] =
                    epival(v, bias ? bias[j] : 0.f, scale, X, (size_t)i * ldx + j, expm);
        }
    }
}

// ---------------- attention scores via exp tables ----------------
// tanh(a+b) = 1 - 2/(1+e^{2a}e^{2b}); Eh=exp(2a), EH=exp(2b) precomputed.
// s[b][l] = swa - 2*sum_m wa[m] * rcp(1 + Eh[b][m]*EH[l][m])
template<int LTILE>
__global__ __launch_bounds__(512) void attn_s(
    int B, const float* __restrict__ Eh,
    const float* __restrict__ EH,
    const float* __restrict__ s_wa_sum,
    const float* __restrict__ Wa,
    float* __restrict__ S)
{
    __shared__ float s_e[8][MD];
    __shared__ float s_wa[MD];
    const int lt = blockIdx.x * LTILE;
    const int b0 = blockIdx.y * 8;
    const int nt = (B - b0 < 8) ? (B - b0) : 8;
    for (int idx = threadIdx.x; idx < MD; idx += 512) s_wa[idx] = Wa[idx];
    for (int i = 0; i < nt; i++)
        for (int idx = threadIdx.x; idx < MD; idx += 512)
            s_e[i][idx] = Eh[(size_t)(b0 + i) * MD + idx];
    __syncthreads();
    const int wv = threadIdx.x >> 6, lane = threadIdx.x & 63;
    const float swa = s_wa_sum[0];
    for (int l = lt + wv; l < lt + LTILE; l += 8) {
        float acc[8] = {};
        const float* er = EH + (size_t)l * MD;
        for (int mc = 0; mc < MD; mc += 256) {
            const int m = mc + lane * 4;
            float4 ev  = *(const float4*)(er + m);
            float4 wa4 = *(const float4*)&s_wa[m];
            #pragma unroll
            for (int i = 0; i < 8; i++) {
                if (i < nt) {
                    float4 se = *(const float4*)&s_e[i][m];
                    float d, r;
                    d = fmaf(se.x, ev.x, 1.0f); r = __builtin_amdgcn_rcpf(d); acc[i] = fmaf(wa4.x, r, acc[i]);
                    d = fmaf(se.y, ev.y, 1.0f); r = __builtin_amdgcn_rcpf(d); acc[i] = fmaf(wa4.y, r, acc[i]);
                    d = fmaf(se.z, ev.z, 1.0f); r = __builtin_amdgcn_rcpf(d); acc[i] = fmaf(wa4.z, r, acc[i]);
                    d = fmaf(se.w, ev.w, 1.0f); r = __builtin_amdgcn_rcpf(d); acc[i] = fmaf(wa4.w, r, acc[i]);
                }
            }
        }
        #pragma unroll
        for (int i = 0; i < 8; i++) {
            if (i < nt) {
                float v = acc[i];
                #pragma unroll
                for (int off = 32; off >= 1; off >>= 1) v += __shfl_xor(v, off);
                if (lane == 0) S[(size_t)(b0 + i) * LD + l] = swa - 2.0f * v;
            }
        }
    }
}

__global__ __launch_bounds__(256) void softmax_rows(float* __restrict__ S)
{
    float* row = S + (size_t)blockIdx.x * LD;
    const int tid = threadIdx.x;
    const int wv = tid >> 6, lane = tid & 63;
    float v0 = row[tid], v1 = row[tid + 256], v2 = row[tid + 512], v3 = row[tid + 768];
    float mx = fmaxf(fmaxf(v0, v1), fmaxf(v2, v3));
    #pragma unroll
    for (int off = 32; off >= 1; off >>= 1) mx = fmaxf(mx, __shfl_xor(mx, off));
    __shared__ float r1[4], r2[4];
    if (lane == 0) r1[wv] = mx;
    __syncthreads();
    mx = fmaxf(fmaxf(r1[0], r1[1]), fmaxf(r1[2], r1[3]));
    float e0 = __expf(v0 - mx), e1 = __expf(v1 - mx), e2 = __expf(v2 - mx), e3 = __expf(v3 - mx);
    float sm = e0 + e1 + e2 + e3;
    #pragma unroll
    for (int off = 32; off >= 1; off >>= 1) sm += __shfl_xor(sm, off);
    if (lane == 0) r2[wv] = sm;
    __syncthreads();
    sm = r2[0] + r2[1] + r2[2] + r2[3];
    float inv = 1.0f / sm;
    row[tid] = e0 * inv; row[tid + 256] = e1 * inv;
    row[tid + 512] = e2 * inv; row[tid + 768] = e3 * inv;
}

// ---------------- elementwise / tree plumbing ----------------
__global__ void gather_children_k(const int* __restrict__ children, int t0,
    const float* __restrict__ Hs, float* __restrict__ hsum, float* __restrict__ hch)
{
    int b = blockIdx.y;
    int m = blockIdx.x * 256 + threadIdx.x;
    int t = t0 + b;
    int c0 = children[2 * t], c1 = children[2 * t + 1];
    float h0 = (c0 >= 0) ? Hs[(size_t)c0 * MD + m] : 0.f;
    float h1 = (c1 >= 0) ? Hs[(size_t)c1 * MD + m] : 0.f;
    hch[(size_t)(2 * b) * MD + m] = h0;
    hch[(size_t)(2 * b + 1) * MD + m] = h1;
    hsum[(size_t)b * MD + m] = h0 + h1;
}

__global__ void cell_finish_k(const int* __restrict__ children, int t0,
    const float* __restrict__ ioupre, const float* __restrict__ fpre,
    const float* __restrict__ x_f, float* __restrict__ Cmat,
    float* __restrict__ hcell)
{
    int b = blockIdx.y;
    int m = blockIdx.x * 256 + threadIdx.x;
    int t = t0 + b;
    const float* ip = ioupre + (size_t)b * 3 * MD;
    float iv = fsig(ip[m]);
    float ov = fsig(ip[MD + m]);
    float uv = ftanh_(ip[2 * MD + m]);
    float xf = x_f[(size_t)t * MD + m];
    float f0 = fsig(fpre[(size_t)(2 * b) * MD + m] + xf);
    float f1 = fsig(fpre[(size_t)(2 * b + 1) * MD + m] + xf);
    int c0 = children[2 * t], c1 = children[2 * t + 1];
    float cc0 = (c0 >= 0) ? Cmat[(size_t)c0 * MD + m] : 0.f;
    float cc1 = (c1 >= 0) ? Cmat[(size_t)c1 * MD + m] : 0.f;
    float c = iv * uv + f0 * cc0 + f1 * cc1;
    Cmat[(size_t)t * MD + m] = c;
    hcell[(size_t)b * MD + m] = ov * ftanh_(c);
}

__global__ void attn_finish_k(int t0, const float* __restrict__ hpart,
    const float* __restrict__ Hsum, const float* __restrict__ hcell,
    float* __restrict__ Hs)
{
    int b = blockIdx.y;
    int m = blockIdx.x * 256 + threadIdx.x;
    Hs[(size_t)(t0 + b) * MD + m] = Hsum[m] - hpart[(size_t)b * MD + m] + hcell[(size_t)b * MD + m];
}

__global__ void colsum_part_k(const float* __restrict__ H, float* __restrict__ part)
{
    int m = blockIdx.x * 256 + threadIdx.x;
    int lb = blockIdx.y;
    float s = 0.f;
    for (int l = lb * 64; l < lb * 64 + 64; l++) s += H[(size_t)l * MD + m];
    part[(size_t)lb * MD + m] = s;
}

__global__ void colsum_reduce_k(const float* __restrict__ part, float* __restrict__ Hsum)
{
    int m = blockIdx.x * 256 + threadIdx.x;
    float s = 0.f;
    for (int lb = 0; lb < 16; lb++) s += part[(size_t)lb * MD + m];
    Hsum[m] = s;
}

__global__ void transpose_split_k(const float* __restrict__ H, float* __restrict__ Ht,
                                  __bf16* __restrict__ Hth, __bf16* __restrict__ Htl)
{
    __shared__ float tile[32][33];
    int mb = blockIdx.x * 32, lb = blockIdx.y * 32;
    int tx = threadIdx.x, ty = threadIdx.y;
    #pragma unroll
    for (int jj = 0; jj < 4; jj++)
        tile[ty + jj * 8][tx] = H[(size_t)(lb + ty + jj * 8) * MD + mb + tx];
    __syncthreads();
    #pragma unroll
    for (int jj = 0; jj < 4; jj++) {
        float v = tile[tx][ty + jj * 8];
        size_t idx = (size_t)(mb + ty + jj * 8) * LD + lb + tx;
        Ht[idx] = v;
        __bf16 h = (__bf16)v;
        Hth[idx] = h;
        Htl[idx] = (__bf16)(v - (float)h);
    }
}

__global__ void sumwa_k(const float* __restrict__ Wa, float* __restrict__ out)
{
    int tid = threadIdx.x;
    float v = Wa[tid] + Wa[tid + 256] + Wa[tid + 512] + Wa[tid + 768];
    #pragma unroll
    for (int off = 32; off >= 1; off >>= 1) v += __shfl_xor(v, off);
    __shared__ float r[4];
    if ((tid & 63) == 0) r[tid >> 6] = v;
    __syncthreads();
    if (tid == 0) out[0] = r[0] + r[1] + r[2] + r[3];
}

__global__ void final_copy_k(const float* __restrict__ Cmat, float* __restrict__ out)
{
    int m = blockIdx.x * 256 + threadIdx.x;
    out[m] = Cmat[m];              // C[0]
    out[1024 + m] = out[2048 + m]; // Hs[0]
}

// ---------------- dispatch helper ----------------
static inline void mmx(const float* A, int lda, int I,
                       const float* Wf, int ldwf,
                       const __bf16* Wh, const __bf16* Wl,
                       const float* bias, const float* X, int ldx,
                       float* C, int ldc, int J, int K, float scale, int expm,
                       hipStream_t s)
{
    if (I <= 32) {
        gemv_nt<32><<<J / 4, 256, 0, s>>>(A, lda, I, Wf, ldwf, bias, X, ldx, C, ldc, K, scale, expm);
    } else {
        int b128 = (J / 128) * ((I + 127) / 128);
        if (b128 >= 192)
            gemm_mfma<<<dim3(J / 128, (I + 127) / 128), 256, 0, s>>>(
                A, lda, Wh, Wl, bias, X, ldx, C, ldc, I, K, scale, expm);
        else
            gemm64_mfma<<<dim3(J / 64, (I + 63) / 64), 256, 0, s>>>(
                A, lda, Wh, Wl, bias, X, ldx, C, ldc, I, K, scale, expm);
    }
}

extern "C" void kernel_launch(void* const* d_in, const int* in_sizes, int n_in,
                              void* d_out, int out_size, void* d_ws, size_t ws_size,
                              hipStream_t stream)
{
    const float* inputs   = (const float*)d_in[0];
    const float* Hmat     = (const float*)d_in[1];
    const int*   children = (const int*)d_in[2];
    const float* ioux_w   = (const float*)d_in[3];
    const float* ioux_b   = (const float*)d_in[4];
    const float* iouh_w   = (const float*)d_in[5];
    const float* iouh_b   = (const float*)d_in[6];
    const float* fx_w     = (const float*)d_in[7];
    const float* fx_b     = (const float*)d_in[8];
    const float* fh_w     = (const float*)d_in[9];
    const float* fh_b     = (const float*)d_in[10];
    const float* Wa       = (const float*)d_in[11];
    const float* attnh_w  = (const float*)d_in[12];
    const float* attnh_b  = (const float*)d_in[13];

    float* out = (float*)d_out;
    float* Hs  = out + 2048;   // Hs (N*M) lives in d_out

    // ---- workspace layout ----
    float* p = (float*)d_ws;
    float* x_f    = p;  p += (size_t)ND * MD;          // 2M
    float* x_iou  = p;  p += (size_t)ND * 3 * MD;      // 6M
    float* EHbuf  = p;  p += (size_t)LD * MD;          // exp(2*(H@W2^T+b))
    float* Ht     = p;  p += (size_t)MD * LD;
    float* Cmat   = p;  p += (size_t)ND * MD;
    float* hsumb  = p;  p += (size_t)1024 * MD;
    float* hchb   = p;  p += (size_t)2048 * MD;
    float* ioupre = p;  p += (size_t)1024 * 3 * MD;
    float* fpre   = p;  p += (size_t)2048 * MD;
    float* hcell  = p;  p += (size_t)1024 * MD;
    float* Ehbuf  = p;  p += (size_t)1024 * MD;        // exp(2*hcell@W1^T)
    float* Sbuf   = p;  p += (size_t)1024 * LD;
    float* hpart  = p;  p += (size_t)1024 * MD;
    float* Hsum   = p;  p += MD;
    float* part16 = p;  p += 16 * MD;
    float* S_wa   = p;  p += 8;
    __bf16* q = (__bf16*)p;
    __bf16* iouhH = q; q += (size_t)3 * MD * MD;
    __bf16* iouhL = q; q += (size_t)3 * MD * MD;
    __bf16* iouxH = q; q += (size_t)3 * MD * MD;
    __bf16* iouxL = q; q += (size_t)3 * MD * MD;
    __bf16* fxH   = q; q += (size_t)MD * MD;
    __bf16* fxL   = q; q += (size_t)MD * MD;
    __bf16* fhH   = q; q += (size_t)MD * MD;
    __bf16* fhL   = q; q += (size_t)MD * MD;
    __bf16* W1H   = q; q += (size_t)MD * MD;
    __bf16* W1L   = q; q += (size_t)MD * MD;
    __bf16* W2H   = q; q += (size_t)MD * MD;
    __bf16* W2L   = q; q += (size_t)MD * MD;
    __bf16* HtH   = q; q += (size_t)MD * LD;
    __bf16* HtL   = q; q += (size_t)MD * LD;

    // ---- one-time: splits & precomputes ----
    split_w_k<<<dim3(4, 3 * MD), 256, 0, stream>>>(iouh_w, MD, iouhH, iouhL, MD);
    split_w_k<<<dim3(4, 3 * MD), 256, 0, stream>>>(ioux_w, MD, iouxH, iouxL, MD);
    split_w_k<<<dim3(4, MD), 256, 0, stream>>>(fx_w, MD, fxH, fxL, MD);
    split_w_k<<<dim3(4, MD), 256, 0, stream>>>(fh_w, MD, fhH, fhL, MD);
    split_w_k<<<dim3(4, MD), 256, 0, stream>>>(attnh_w, 2 * MD, W1H, W1L, MD);
    split_w_k<<<dim3(4, MD), 256, 0, stream>>>(attnh_w + MD, 2 * MD, W2H, W2L, MD);
    transpose_split_k<<<dim3(32, 32), dim3(32, 8), 0, stream>>>(Hmat, Ht, HtH, HtL);
    sumwa_k<<<1, 256, 0, stream>>>(Wa, S_wa);
    colsum_part_k<<<dim3(4, 16), 256, 0, stream>>>(Hmat, part16);
    colsum_reduce_k<<<4, 256, 0, stream>>>(part16, Hsum);

    // x_f = inputs@fx^T + fx_b ; x_iou = inputs@ioux^T + ioux_b
    mmx(inputs, MD, ND, fx_w, MD, fxH, fxL, fx_b, nullptr, 0, x_f, MD, MD, MD, 1.0f, 0, stream);
    mmx(inputs, MD, ND, ioux_w, MD, iouxH, iouxL, ioux_b, nullptr, 0, x_iou, 3 * MD, 3 * MD, MD, 1.0f, 0, stream);
    // EH = exp(2*(H@W2^T + attnh_b))
    mmx(Hmat, MD, LD, attnh_w + MD, 2 * MD, W2H, W2L, attnh_b, nullptr, 0, EHbuf, MD, MD, MD, 2.0f, 1, stream);

    // ---- level-parallel tree scan (deepest first) ----
    static const int lv_t0[12] = {2047, 1023, 511, 255, 127, 63, 31, 15, 7, 3, 1, 0};
    static const int lv_B [12] = {1, 1024, 512, 256, 128, 64, 32, 16, 8, 4, 2, 1};
    for (int li = 0; li < 12; li++) {
        int t0 = lv_t0[li], B = lv_B[li];
        gather_children_k<<<dim3(4, B), 256, 0, stream>>>(children, t0, Hs, hsumb, hchb);
        // iou = hsum@iouh^T + iouh_b + x_iou[t0..]
        mmx(hsumb, MD, B, iouh_w, MD, iouhH, iouhL, iouh_b,
            x_iou + (size_t)t0 * 3 * MD, 3 * MD, ioupre, 3 * MD, 3 * MD, MD, 1.0f, 0, stream);
        // fpre = hch@fh^T + fh_b
        mmx(hchb, MD, 2 * B, fh_w, MD, fhH, fhL, fh_b, nullptr, 0, fpre, MD, MD, MD, 1.0f, 0, stream);
        cell_finish_k<<<dim3(4, B), 256, 0, stream>>>(children, t0, ioupre, fpre, x_f, Cmat, hcell);
        // Eh = exp(2*hcell@W1^T)
        mmx(hcell, MD, B, attnh_w, 2 * MD, W1H, W1L, nullptr, nullptr, 0, Ehbuf, MD, MD, MD, 2.0f, 1, stream);
        if (B >= 128)
            attn_s<64><<<dim3(LD / 64, (B + 7) / 8), 512, 0, stream>>>(B, Ehbuf, EHbuf, S_wa, Wa, Sbuf);
        else
            attn_s<8><<<dim3(LD / 8, (B + 7) / 8), 512, 0, stream>>>(B, Ehbuf, EHbuf, S_wa, Wa, Sbuf);
        softmax_rows<<<B, 256, 0, stream>>>(Sbuf);
        // hpart = p@H (via Ht)
        mmx(Sbuf, LD, B, Ht, LD, HtH, HtL, nullptr, nullptr, 0, hpart, MD, MD, LD, 1.0f, 0, stream);
        attn_finish_k<<<dim3(4, B), 256, 0, stream>>>(t0, hpart, Hsum, hcell, Hs);
    }
    final_copy_k<<<4, 256, 0, stream>>>(Cmat, out);
}